// Round 7
// baseline (1538.162 us; speedup 1.0000x reference)
//
#include <hip/hip_runtime.h>
#include <hip/hip_bf16.h>
#include <stdint.h>
#include <math.h>

typedef __hip_bfloat16 bf16;
typedef __attribute__((ext_vector_type(4))) float floatx4;
typedef __attribute__((ext_vector_type(8))) __bf16 bf16x8;
typedef __attribute__((ext_vector_type(4))) __bf16 bf16x4;

typedef __attribute__((address_space(1))) void gvoid_t;
typedef __attribute__((address_space(3))) void lvoid_t;

__device__ __forceinline__ void gl_lds16(const void* g, void* l){
  __builtin_amdgcn_global_load_lds((gvoid_t*)g, (lvoid_t*)l, 16, 0, 0);
}

__device__ __forceinline__ float gelu_f(float v){
  float u = 0.7978845608028654f*(v + 0.044715f*v*v*v);
  float e = __expf(2.0f*u);
  return v*(1.0f - 1.0f/(e+1.0f));
}

// ---------------- GEMM: C[M,N] = A[M,K](bf16) @ BT[N,K](bf16) + bias ----------
// MODE 0: bf16 C = acc+bias
// MODE 1: bf16 C = gelu(acc+bias)
// MODE 3: bf16 C = (acc+bias) * (n0<1152 ? qs : 1)   [QKV with folded q-scale]
// MODE 4: bf16 partial C[s][M][N] = acc + (s==0 ? bias : 0)   [split-K, blockIdx.z = s]
//
// 256x128 tile, 4 waves of 128x64 (acc[8][4]), ring-3 (BK=32, 3x24KB = 72KB, 2 blk/CU).
// R7: XCD-chunk traversal = GROUP_M=4, m-fastest, n-outer. Each XCD's contiguous
// chunk walks a 4(m) x C(n) rectangle column by column: A-quad (2.36MB) stays L2-
// resident, B panels stream with immediate 4x reuse -> working set ~2.7MB < 4MB L2
// (was 8x9 rect = 7.4MB -> thrash, FETCH 115MB, vmcnt gate exposed ~1500cy misses).
template<int MODE>
__global__ __launch_bounds__(256,2)
void gemm_bf16(const bf16* __restrict__ A, const bf16* __restrict__ BT,
               const float* __restrict__ bias, void* __restrict__ C,
               int N, int K, int kc, float qs)
{
  __shared__ __align__(128) char ldsm[73728];   // 3 x 24576
  const int tid  = threadIdx.x;
  const int wave = tid>>6, lane = tid&63;
  const int quad = lane>>4, l16 = lane&15;

  // ---- T1: bijective XCD-chunked swizzle + GROUP_M=4 m-fastest traversal ----
  // all grids here have nwg % 8 == 0 and gridDim.y % 4 == 0
  int bm, bn;
  {
    const int nx = gridDim.x;
    const int nwg = nx * gridDim.y;
    int lid = blockIdx.x + nx*blockIdx.y;
    const int q = nwg >> 3;
    const int xcd = lid & 7, off = lid >> 3;
    lid = xcd*q + off;                  // contiguous chunk per XCD
    const int per = nx << 2;            // blocks per 4-row m-group
    const int g   = lid / per;
    const int rem = lid - g*per;
    bm = (g<<2) + (rem & 3);            // m fastest within quad -> A-quad L2-resident
    bn = rem >> 2;                      // n outer -> B panel streams, 4x back-to-back reuse
  }
  const int m0 = bm*256, n0 = bn*128;

  const int s  = blockIdx.z;
  const int kb = s*kc;
  const int ke = min(K, kb + kc);
  const int T  = (ke - kb) >> 5;        // all chunks are multiples of 32
  const int wm = (wave&1)*128, wn = (wave>>1)*64;
  floatx4 acc[8][4] = {};

  // ---- staging addresses (pre-swizzled global source) ----
  // thread t covers rows (t>>2) + j*64, 16B slot (t&3) holding LOGICAL slot (t&3)^(row&3)
  const int grow  = tid>>2;
  const int gslot = (tid&3) ^ (grow&3);
  const bf16* aBase = A  + (size_t)(m0 + grow)*K + kb + gslot*8;
  const bf16* bBase = BT + (size_t)(n0 + grow)*K + kb + gslot*8;
  const size_t rowK64 = (size_t)64*K;
  char* ldw = ldsm + (wave<<10);

  // ---- swizzled ds_read offsets: byte = row*64 + ((quad^(row&3))*16), row&3==l16&3 ----
  const int swz = (quad ^ (l16&3))<<4;
  const int aRd = ((wm + l16)<<6) + swz;            // A region at +0     (16KB, 256 rows)
  const int bRd = 16384 + ((wn + l16)<<6) + swz;    // B region at +16384 (8KB, 128 rows)

  auto stage = [&](int tp, int buf){
    char* ld = ldw + buf*24576;
    const bf16* ga = aBase + (size_t)tp*32;
    const bf16* gb = bBase + (size_t)tp*32;
    gl_lds16(ga,              ld);
    gl_lds16(ga +   rowK64,   ld + 4096);
    gl_lds16(ga + 2*rowK64,   ld + 8192);
    gl_lds16(ga + 3*rowK64,   ld + 12288);
    gl_lds16(gb,              ld + 16384);
    gl_lds16(gb +   rowK64,   ld + 20480);
  };

  // prologue: tiles 0,1 in flight (12 loads)
  stage(0,0); stage(1,1);

  int cur = 0, nxt = 2;
  for (int t=0; t<T; ++t){
    if (t < T-1) asm volatile("s_waitcnt vmcnt(6)" ::: "memory");  // tile t done; t+1 in flight
    else         asm volatile("s_waitcnt vmcnt(0)" ::: "memory");
    asm volatile("s_barrier" ::: "memory");           // publish LDS to all waves
    const char* bufb = ldsm + cur*24576;
    bf16x8 af[8], bfr[4];
#pragma unroll
    for (int i=0;i<8;i++) af[i]  = *(const bf16x8*)(bufb + aRd + (i<<10));
#pragma unroll
    for (int j=0;j<4;j++) bfr[j] = *(const bf16x8*)(bufb + bRd + (j<<10));
    if (t+2 < T) stage(t+2, nxt);
    __builtin_amdgcn_s_setprio(1);
#pragma unroll
    for (int i=0;i<8;i++)
#pragma unroll
      for (int j=0;j<4;j++)
        acc[i][j] = __builtin_amdgcn_mfma_f32_16x16x32_bf16(af[i], bfr[j], acc[i][j], 0,0,0);
    __builtin_amdgcn_s_setprio(0);
    cur = (cur==2) ? 0 : cur+1;
    nxt = (nxt==2) ? 0 : nxt+1;
  }

  const float scale = (MODE==3 && n0<1152) ? qs : 1.0f;
#pragma unroll
  for (int i=0;i<8;i++){
    const int gr0 = m0 + wm + i*16 + quad*4;
#pragma unroll
    for (int j=0;j<4;j++){
      const int gc = n0 + wn + j*16 + l16;
      const float bv = (MODE!=4 || s==0) ? bias[gc] : 0.f;
#pragma unroll
      for (int r=0;r<4;r++){
        const int gr = gr0 + r;
        float v = acc[i][j][r] + bv;
        if constexpr (MODE==1) v = gelu_f(v);
        if constexpr (MODE==3) v *= scale;
        if constexpr (MODE==4){
          ((bf16*)C)[((size_t)s*4096 + gr)*N + gc] = __float2bfloat16(v);
        } else {
          ((bf16*)C)[(size_t)gr*N + gc] = __float2bfloat16(v);
        }
      }
    }
  }
}

// ---------------- fused split-K reduce + residual + LayerNorm ----------------
template<int OUTF32, int WRITEX>
__global__ __launch_bounds__(256)
void ln_red(const float* __restrict__ base, unsigned bmask,
            const bf16* __restrict__ part, int ks,
            const float* __restrict__ g, const float* __restrict__ b,
            float* __restrict__ xw, void* __restrict__ out)
{
  const int row  = blockIdx.x*4 + (threadIdx.x>>6);
  const int lane = threadIdx.x & 63;
  const float2* br = (const float2*)base + (size_t)(row & bmask)*576;
  float2 v[9];
#pragma unroll
  for (int r=0;r<9;r++) v[r] = br[r*64+lane];
  for (int s=0;s<ks;s++){
    const __hip_bfloat162* pr = (const __hip_bfloat162*)part + ((size_t)s*4096 + row)*576;
#pragma unroll
    for (int r=0;r<9;r++){
      const float2 pv = __bfloat1622float2(pr[r*64+lane]);
      v[r].x += pv.x; v[r].y += pv.y;
    }
  }
  float sm=0.f, ss=0.f;
#pragma unroll
  for (int r=0;r<9;r++){
    sm += v[r].x + v[r].y;
    ss += v[r].x*v[r].x + v[r].y*v[r].y;
  }
#pragma unroll
  for (int m=1;m<64;m<<=1){ sm += __shfl_xor(sm,m,64); ss += __shfl_xor(ss,m,64); }
  const float mean = sm*(1.0f/1152.0f);
  const float rs = rsqrtf(ss*(1.0f/1152.0f) - mean*mean + 1e-6f);
  const float2* gr2 = (const float2*)g;
  const float2* br2 = (const float2*)b;
#pragma unroll
  for (int r=0;r<9;r++){
    const int c = r*64+lane;
    if constexpr (WRITEX) ((float2*)xw)[(size_t)row*576 + c] = v[r];
    const float2 gg = gr2[c], bb = br2[c];
    const float o0 = (v[r].x-mean)*rs*gg.x + bb.x;
    const float o1 = (v[r].y-mean)*rs*gg.y + bb.y;
    if constexpr (OUTF32){
      ((float2*)out)[(size_t)row*576 + c] = make_float2(o0, o1);
    } else {
      __hip_bfloat162 hv;
      hv.x = __float2bfloat16(o0); hv.y = __float2bfloat16(o1);
      ((__hip_bfloat162*)out)[(size_t)row*576 + c] = hv;
    }
  }
}

// ---------------- im2col for 14x14 stride-14 conv: [4096, 608] bf16 ----
__global__ __launch_bounds__(256)
void im2col_kernel(const float* __restrict__ img, bf16* __restrict__ out)
{
  const int idx = blockIdx.x*256 + threadIdx.x;  // 4096*608
  const int kk = idx % 608;
  const int rr = idx / 608;
  float v = 0.f;
  if (kk < 588){
    const int bt = rr >> 10, n = rr & 1023;
    const int py = n >> 5, px = n & 31;
    const int ph = kk / 42;
    const int rem = kk - ph*42;
    const int pw = rem / 3;
    const int c  = rem - pw*3;
    v = img[(((size_t)bt*448 + py*14 + ph)*448 + px*14 + pw)*3 + c];
  }
  out[idx] = __float2bfloat16(v);
}

// ---------------- fp32 [K,N] -> bf16 [Np,Kp] transpose+convert, zero-pad -----------------
__global__ __launch_bounds__(256)
void transpose_cvt(const float* __restrict__ in, bf16* __restrict__ out,
                   int K, int N, int Kp, int Np)
{
  __shared__ float tile[32][33];
  const int nt = blockIdx.x*32, kt = blockIdx.y*32;
  const int r = threadIdx.x>>5, c = threadIdx.x&31;
#pragma unroll
  for (int i=0;i<4;i++){
    const int k = kt + r + i*8, n = nt + c;
    tile[r+i*8][c] = (k<K && n<N) ? in[(size_t)k*N + n] : 0.f;
  }
  __syncthreads();
#pragma unroll
  for (int i=0;i<4;i++){
    const int n = nt + r + i*8, k = kt + c;
    out[(size_t)n*Kp + k] = __float2bfloat16(tile[c][r+i*8]);
  }
}

// ---------------- bias packing + zero-buffer init ---------------
__global__ __launch_bounds__(256)
void pack_biases(const float* __restrict__ bq, const float* __restrict__ bk,
                 const float* __restrict__ bv, const float* __restrict__ b1,
                 int l, float* __restrict__ bqkv, float* __restrict__ b1p,
                 float4* __restrict__ zbuf)
{
  const int i = blockIdx.x*256 + threadIdx.x;
  if (i < 3456){
    float v;
    if (i < 1152)      v = bq[l*1152 + i];
    else if (i < 2304) v = bk[l*1152 + i - 1152];
    else               v = bv[l*1152 + i - 2304];
    bqkv[i] = v;
  }
  if (i < 4352) b1p[i] = (i < 4304) ? b1[l*4304 + i] : 0.f;
  if (i == 0) *zbuf = make_float4(0.f,0.f,0.f,0.f);
}

// -------- v repack transposed: qkv v-cols -> [64 bh][80 dh][1024 n] ------
// pad rows: dh==72 set to ONES (accumulates the softmax denominator in PV),
// dh>72 zero.
__global__ __launch_bounds__(256)
void transpose_v(const bf16* __restrict__ src, bf16* __restrict__ dst)
{
  __shared__ bf16 tile[128][73];
  const int nc = blockIdx.x, bh = blockIdx.y;
  const int bt = bh>>4, hh = bh&15;
  const bf16* s = src + ((size_t)bt*1024 + nc*128)*3456 + 2304 + hh*72;
  for (int e=threadIdx.x; e<128*72; e+=256){
    const int n = e/72, dh = e - n*72;
    tile[n][dh] = s[(size_t)n*3456 + dh];
  }
  __syncthreads();
  bf16* d = dst + (size_t)bh*80*1024 + nc*128;
  const bf16 z  = __float2bfloat16(0.f);
  const bf16 on = __float2bfloat16(1.f);
  for (int e=threadIdx.x; e<80*128; e+=256){
    const int dh = e>>7, n = e&127;
    d[(size_t)dh*1024 + n] = (dh<72) ? tile[n][dh] : (dh==72 ? on : z);
  }
}

// ---------------- flash attention v2: swapped QK^T, lane-local softmax ------
__global__ __launch_bounds__(256,3)
void attn_kernel(const bf16* __restrict__ qkv, const bf16* __restrict__ vb,
                 const float4* __restrict__ zbuf, bf16* __restrict__ outp)
{
  __shared__ bf16 Ks[128*96];   // 24576 B; first 16KB aliased as P-buffer after QK
  __shared__ bf16 Vs[80*128];   // 20480 B
  const int tid = threadIdx.x, wave = tid>>6, lane = tid&63;
  const int quad = lane>>4, l16 = lane&15;
  // T1: XCD-chunked swizzle
  int lid = blockIdx.x + (blockIdx.y<<4);
  lid = ((lid & 7) << 7) + (lid >> 3);
  const int bh = lid >> 4, q0 = (lid & 15) << 6;
  const int bt = bh>>4, hh = bh&15;
  const bf16* vg = vb + (size_t)bh*80*1024;
  bf16x8 af0{}, af1{}, af2{};
  {
    const bf16* qp = qkv + (size_t)(bt*1024 + q0 + wave*16 + l16)*3456 + hh*72 + quad*8;
    af0 = *(const bf16x8*)(qp);
    af1 = *(const bf16x8*)(qp+32);
    if (quad==0) af2 = *(const bf16x8*)(qp+64);
  }
  float mr = -3.0e38f;          // running row-max for q = wave*16+l16 (uniform over quad)
  floatx4 oacc[5] = {};
  const int prow = wave*16 + l16;
  const int hi2 = (l16>>2)&3, lo2 = l16&3;
  char* const psrow = (char*)Ks + prow*256;

  for (int kc=0;kc<8;kc++){
    __syncthreads();   // (A) everyone done with PV reads of Ps/Vs from prev iter
    {
      const char* kcb = (const char*)(qkv + (size_t)(bt*1024 + kc*128)*3456 + 1152 + hh*72);
#pragma unroll
      for (int i=0;i<6;i++){
        const int u = (wave*6+i)*64 + lane;      // 0..1535
        const int row = u/12;
        const int pp = u - row*12;
        const int c = (pp & 12) | ((pp & 3) ^ (row & 3));
        const void* src = (c<9) ? (const void*)(kcb + (size_t)row*6912 + c*16)
                                : (const void*)zbuf;
        gl_lds16(src, (char*)Ks + (size_t)(wave*6+i)*1024);
      }
#pragma unroll
      for (int i=0;i<5;i++){
        const int u = (wave*5+i)*64 + lane;      // 0..1279
        const int row = u>>4;
        const int pp = u & 15;
        const int c = (pp & 8) | ((pp & 7) ^ (row & 7));
        gl_lds16((const char*)vg + (size_t)row*2048 + kc*256 + c*16,
                 (char*)Vs + (size_t)(wave*5+i)*1024);
      }
    }
    __syncthreads();   // (B) tiles staged
    floatx4 sc[8] = {};
    const int ksw = (quad ^ (l16&3))*8;
#pragma unroll
    for (int ct=0;ct<8;ct++){
      const bf16* kr = Ks + (ct*16+l16)*96 + ksw;
      sc[ct] = __builtin_amdgcn_mfma_f32_16x16x32_bf16(*(const bf16x8*)(kr   ), af0, sc[ct],0,0,0);
      sc[ct] = __builtin_amdgcn_mfma_f32_16x16x32_bf16(*(const bf16x8*)(kr+32), af1, sc[ct],0,0,0);
      sc[ct] = __builtin_amdgcn_mfma_f32_16x16x32_bf16(*(const bf16x8*)(kr+64), af2, sc[ct],0,0,0);
    }
    // row-max: local over 32 values, then combine quads (lane^16, lane^32)
    float cm = sc[0][0];
#pragma unroll
    for (int ct=0;ct<8;ct++)
#pragma unroll
      for (int r=0;r<4;r++) cm = fmaxf(cm, sc[ct][r]);
    cm = fmaxf(cm, __shfl_xor(cm, 16, 64));
    cm = fmaxf(cm, __shfl_xor(cm, 32, 64));
    // T13 defer-max
    if (!__all(cm <= mr + 8.0f)){
      const float mn = fmaxf(mr, cm);
      const float alv = exp2f(mr - mn);   // 0 on first iteration
      mr = mn;
      float alb[4];
#pragma unroll
      for (int r=0;r<4;r++) alb[r] = __shfl(alv, quad*4 + r, 64);
#pragma unroll
      for (int t=0;t<5;t++)
#pragma unroll
        for (int r=0;r<4;r++) oacc[t][r] *= alb[r];
    }
    __syncthreads();   // (C) all waves done reading Ks -> safe to write P into alias
    // P = exp2(sc - mr) -> bf16, one swizzled b64 write per ct (k quad*4..+3)
#pragma unroll
    for (int ct=0;ct<8;ct++){
      bf16x4 pk;
      pk[0] = (__bf16)exp2f(sc[ct][0] - mr);
      pk[1] = (__bf16)exp2f(sc[ct][1] - mr);
      pk[2] = (__bf16)exp2f(sc[ct][2] - mr);
      pk[3] = (__bf16)exp2f(sc[ct][3] - mr);
      *(bf16x4*)(psrow + (((ct^hi2)<<5) | ((quad^lo2)<<3))) = pk;
    }
    // PV: rebuild A-fragments from the swizzled P-buffer (2x b64 per ks)
#pragma unroll
    for (int ks=0;ks<4;ks++){
      const int ct0 = 2*ks + (quad>>1);
      const int g0 = (quad&1)*2;
      const bf16x4 plo = *(const bf16x4*)(psrow + (((ct0^hi2)<<5) | (((g0  )^lo2)<<3)));
      const bf16x4 phi = *(const bf16x4*)(psrow + (((ct0^hi2)<<5) | (((g0+1)^lo2)<<3)));
      bf16x8 pf;
      pf[0]=plo[0]; pf[1]=plo[1]; pf[2]=plo[2]; pf[3]=plo[3];
      pf[4]=phi[0]; pf[5]=phi[1]; pf[6]=phi[2]; pf[7]=phi[3];
      const int c = ks*4 + quad;
      const int pp = (c & 8) | ((c & 7) ^ (l16 & 7));
#pragma unroll
      for (int t=0;t<5;t++){
        const bf16x8 vf = *(const bf16x8*)(Vs + (t*16+l16)*128 + pp*8);
        oacc[t] = __builtin_amdgcn_mfma_f32_16x16x32_bf16(pf, vf, oacc[t],0,0,0);
      }
    }
  }
  // denominator lives in oacc[4][r] at lanes l16==8 (dh==72 ones-row)
  float inv[4];
#pragma unroll
  for (int r=0;r<4;r++){
    const float lr = __shfl(oacc[4][r], quad*16 + 8, 64);
    inv[r] = 1.0f / lr;
  }
#pragma unroll
  for (int t=0;t<5;t++){
    const int dh = t*16+l16;
    if (dh < 72){
#pragma unroll
      for (int r=0;r<4;r++){
        const int q = wave*16 + quad*4 + r;
        const float v = oacc[t][r] * inv[r];
        outp[((size_t)bt*1024 + q0 + q)*1152 + hh*72 + dh] = __float2bfloat16(v);
      }
    }
  }
}

extern "C" void kernel_launch(void* const* d_in, const int* in_sizes, int n_in,
                              void* d_out, int out_size, void* d_ws, size_t ws_size,
                              hipStream_t stream)
{
  (void)in_sizes; (void)n_in; (void)out_size; (void)ws_size;
  const float* images = (const float*)d_in[0];
  const float* conv_w = (const float*)d_in[1];
  const float* conv_b = (const float*)d_in[2];
  const float* pos_emb= (const float*)d_in[3];
  const float* ln1_g  = (const float*)d_in[4];
  const float* ln1_b  = (const float*)d_in[5];
  const float* Wq     = (const float*)d_in[6];
  const float* bq     = (const float*)d_in[7];
  const float* Wk     = (const float*)d_in[8];
  const float* bk     = (const float*)d_in[9];
  const float* Wv     = (const float*)d_in[10];
  const float* bv     = (const float*)d_in[11];
  const float* Wo     = (const float*)d_in[12];
  const float* bo     = (const float*)d_in[13];
  const float* ln2_g  = (const float*)d_in[14];
  const float* ln2_b  = (const float*)d_in[15];
  const float* W1     = (const float*)d_in[16];
  const float* b1     = (const float*)d_in[17];
  const float* W2     = (const float*)d_in[18];
  const float* b2     = (const float*)d_in[19];
  const float* lnf_g  = (const float*)d_in[20];
  const float* lnf_b  = (const float*)d_in[21];

  char* p = (char*)d_ws;
  auto take = [&](size_t nbytes)->char*{ char* q = p; p += (nbytes + 255) & ~(size_t)255; return q; };
  float* xw   = (float*)take(4096ull*1152*4);
  bf16* hbuf  = (bf16*) take(4096ull*1152*2);
  bf16* h1    = (bf16*) take(4096ull*4352*2);
  bf16* qkvr  = h1;
  bf16* vbuf  = (bf16*) take(64ull*80*1024*2);
  bf16* imcol = vbuf;
  bf16* aout  = (bf16*) take(4096ull*1152*2);
  bf16* WqkvT = (bf16*) take(3456ull*1152*2);
  bf16* WoT   = (bf16*) take(1152ull*1152*2);
  bf16* W1T   = (bf16*) take(4352ull*1152*2);
  bf16* cwT   = W1T;
  bf16* W2T   = (bf16*) take(1152ull*4352*2);
  bf16* Ppart = (bf16*) take(4ull*4096*1152*2);  // bf16 split-K partials (max ks=4)
  float* bqkv = (float*)take(3456*4);
  float* b1p  = (float*)take(4352*4);
  float4* zbuf= (float4*)take(256);

  const float qscale = 1.4426950408889634f / sqrtf(72.0f);

  im2col_kernel<<<9728, 256, 0, stream>>>(images, imcol);
  transpose_cvt<<<dim3(36,19), 256, 0, stream>>>(conv_w, cwT, 588, 1152, 608, 1152);
  gemm_bf16<4><<<dim3(9,16,2), 256, 0, stream>>>(imcol, cwT, conv_b, Ppart, 1152, 608, 320, 0.f);

  for (int l=0;l<4;l++){
    transpose_cvt<<<dim3(36,36), 256, 0, stream>>>(Wq + (size_t)l*1152*1152, WqkvT,                1152,1152,1152,1152);
    transpose_cvt<<<dim3(36,36), 256, 0, stream>>>(Wk + (size_t)l*1152*1152, WqkvT + 1152ull*1152, 1152,1152,1152,1152);
    transpose_cvt<<<dim3(36,36), 256, 0, stream>>>(Wv + (size_t)l*1152*1152, WqkvT + 2304ull*1152, 1152,1152,1152,1152);
    transpose_cvt<<<dim3(36,36), 256, 0, stream>>>(Wo + (size_t)l*1152*1152, WoT, 1152,1152,1152,1152);
    transpose_cvt<<<dim3(136,36),256, 0, stream>>>(W1 + (size_t)l*1152*4304, W1T, 1152,4304,1152,4352);
    transpose_cvt<<<dim3(36,136),256, 0, stream>>>(W2 + (size_t)l*4304*1152, W2T, 4304,1152,4352,1152);
    pack_biases<<<17,256,0,stream>>>(bq,bk,bv,b1,l,bqkv,b1p,zbuf);

    if (l==0)
      ln_red<0,1><<<1024,256,0,stream>>>(pos_emb, 1023u, Ppart, 2, ln1_g, ln1_b, xw, hbuf);
    else
      ln_red<0,1><<<1024,256,0,stream>>>(xw, 4095u, Ppart, 4, ln1_g + l*1152, ln1_b + l*1152, xw, hbuf);

    gemm_bf16<3><<<dim3(27,16,1),256,0,stream>>>(hbuf, WqkvT, bqkv, qkvr, 3456, 1152, 1152, qscale);
    transpose_v<<<dim3(8,64),256,0,stream>>>(qkvr, vbuf);
    attn_kernel<<<dim3(16,64),256,0,stream>>>(qkvr, vbuf, zbuf, aout);
    gemm_bf16<4><<<dim3(9,16,3),256,0,stream>>>(aout, WoT, bo + l*1152, Ppart, 1152, 1152, 384, 0.f);
    ln_red<0,1><<<1024,256,0,stream>>>(xw, 4095u, Ppart, 3, ln2_g + l*1152, ln2_b + l*1152, xw, hbuf);

    gemm_bf16<1><<<dim3(34,16,1),256,0,stream>>>(hbuf, W1T, b1p, h1, 4352, 1152, 1152, 0.f);
    gemm_bf16<4><<<dim3(9,16,4),256,0,stream>>>(h1, W2T, b2 + l*1152, Ppart, 1152, 4352, 1088, 0.f);
  }
  ln_red<1,0><<<1024,256,0,stream>>>(xw, 4095u, Ppart, 4, lnf_g, lnf_b, nullptr, (float*)d_out);
}

// Round 8
// 1459.430 us; speedup vs baseline: 1.0539x; 1.0539x over previous
//
#include <hip/hip_runtime.h>
#include <hip/hip_bf16.h>
#include <stdint.h>
#include <math.h>

typedef __hip_bfloat16 bf16;
typedef __attribute__((ext_vector_type(4))) float floatx4;
typedef __attribute__((ext_vector_type(8))) __bf16 bf16x8;
typedef __attribute__((ext_vector_type(4))) __bf16 bf16x4;

typedef __attribute__((address_space(1))) void gvoid_t;
typedef __attribute__((address_space(3))) void lvoid_t;

__device__ __forceinline__ void gl_lds16(const void* g, void* l){
  __builtin_amdgcn_global_load_lds((gvoid_t*)g, (lvoid_t*)l, 16, 0, 0);
}

__device__ __forceinline__ float gelu_f(float v){
  float u = 0.7978845608028654f*(v + 0.044715f*v*v*v);
  float e = __expf(2.0f*u);
  return v*(1.0f - 1.0f/(e+1.0f));
}

// ---------------- GEMM: C[M,N] = A[M,K](bf16) @ BT[N,K](bf16) + bias ----------
// MODE 0: bf16 C = acc+bias
// MODE 1: bf16 C = gelu(acc+bias)
// MODE 3: bf16 C = (acc+bias) * (n0<1152 ? qs : 1)   [QKV with folded q-scale]
// MODE 4: bf16 partial C[s][M][N] = acc + (s==0 ? bias : 0)   [split-K, blockIdx.z = s]
//
// R8: 128x128 tile, ring-3 (3 x 16KB = 48KB) -> 3 blocks/CU (was 2). R7 showed
// ~3000cy/iter of unattributed wait at 2 blocks/CU across 3 structural variants
// (MfmaUtil pinned 21-22%): TLP starvation at the vmcnt gate. 3 blocks/CU = 3
// waves/SIMD gives the scheduler a third independent stream to fill gate holes
// (m114 mechanism). Keeps R7's GROUP_M=4 m-fastest XCD traversal (FETCH fix).
// Per iter: gate vmcnt(4) [tile t+1 in flight], s_barrier, 8x ds_read_b128
// (swizzled), stage tile t+2 (4x global_load_lds), setprio(1), 16 MFMA, setprio(0).
template<int MODE>
__global__ __launch_bounds__(256,3)
void gemm_bf16(const bf16* __restrict__ A, const bf16* __restrict__ BT,
               const float* __restrict__ bias, void* __restrict__ C,
               int N, int K, int kc, float qs)
{
  __shared__ __align__(128) char ldsm[49152];   // 3 x 16384
  const int tid  = threadIdx.x;
  const int wave = tid>>6, lane = tid&63;
  const int quad = lane>>4, l16 = lane&15;

  // ---- T1: bijective XCD-chunked swizzle + GROUP_M=4 m-fastest traversal ----
  // all grids here have nwg % 8 == 0 and gridDim.y % 4 == 0
  int bm, bn;
  {
    const int nx = gridDim.x;
    const int nwg = nx * gridDim.y;
    int lid = blockIdx.x + nx*blockIdx.y;
    const int q = nwg >> 3;
    const int xcd = lid & 7, off = lid >> 3;
    lid = xcd*q + off;                  // contiguous chunk per XCD
    const int per = nx << 2;            // blocks per 4-row m-group
    const int g   = lid / per;
    const int rem = lid - g*per;
    bm = (g<<2) + (rem & 3);            // m fastest within quad -> A-quad L2-resident
    bn = rem >> 2;                      // n outer -> B panel streams with 4x reuse
  }
  const int m0 = bm*128, n0 = bn*128;

  const int s  = blockIdx.z;
  const int kb = s*kc;
  const int ke = min(K, kb + kc);
  const int T  = (ke - kb) >> 5;        // all chunks are multiples of 32
  const int wm = (wave&1)*64, wn = (wave>>1)*64;
  floatx4 acc[4][4] = {};

  // ---- staging addresses (pre-swizzled global source) ----
  // thread t covers rows (t>>2) and (t>>2)+64, 16B slot (t&3) holding
  // LOGICAL slot (t&3)^(row&3)
  const int grow  = tid>>2;
  const int gslot = (tid&3) ^ (grow&3);
  const bf16* aBase = A  + (size_t)(m0 + grow)*K + kb + gslot*8;
  const bf16* bBase = BT + (size_t)(n0 + grow)*K + kb + gslot*8;
  const size_t rowK64 = (size_t)64*K;
  char* ldw = ldsm + (wave<<10);

  // ---- swizzled ds_read offsets: byte = row*64 + ((quad^(row&3))*16), row&3==l16&3 ----
  const int swz = (quad ^ (l16&3))<<4;
  const int aRd = ((wm + l16)<<6) + swz;           // A region at +0    (8KB, 128 rows)
  const int bRd = 8192 + ((wn + l16)<<6) + swz;    // B region at +8192 (8KB, 128 rows)

  auto stage = [&](int tp, int buf){
    char* ld = ldw + (buf<<14);
    const bf16* ga = aBase + (size_t)tp*32;
    const bf16* gb = bBase + (size_t)tp*32;
    gl_lds16(ga,          ld);
    gl_lds16(ga + rowK64, ld + 4096);
    gl_lds16(gb,          ld + 8192);
    gl_lds16(gb + rowK64, ld + 12288);
  };

  // prologue: tiles 0,1 in flight (8 loads)
  stage(0,0); stage(1,1);

  int cur = 0, nxt = 2;
  for (int t=0; t<T; ++t){
    if (t < T-1) asm volatile("s_waitcnt vmcnt(4)" ::: "memory");  // tile t done; t+1 in flight
    else         asm volatile("s_waitcnt vmcnt(0)" ::: "memory");
    asm volatile("s_barrier" ::: "memory");           // publish LDS to all waves
    const char* bufb = ldsm + (cur<<14);
    bf16x8 af[4], bfr[4];
#pragma unroll
    for (int i=0;i<4;i++) af[i]  = *(const bf16x8*)(bufb + aRd + (i<<10));
#pragma unroll
    for (int j=0;j<4;j++) bfr[j] = *(const bf16x8*)(bufb + bRd + (j<<10));
    if (t+2 < T) stage(t+2, nxt);
    __builtin_amdgcn_s_setprio(1);
#pragma unroll
    for (int i=0;i<4;i++)
#pragma unroll
      for (int j=0;j<4;j++)
        acc[i][j] = __builtin_amdgcn_mfma_f32_16x16x32_bf16(af[i], bfr[j], acc[i][j], 0,0,0);
    __builtin_amdgcn_s_setprio(0);
    cur = (cur==2) ? 0 : cur+1;
    nxt = (nxt==2) ? 0 : nxt+1;
  }

  const float scale = (MODE==3 && n0<1152) ? qs : 1.0f;
#pragma unroll
  for (int i=0;i<4;i++){
    const int gr0 = m0 + wm + i*16 + quad*4;
#pragma unroll
    for (int j=0;j<4;j++){
      const int gc = n0 + wn + j*16 + l16;
      const float bv = (MODE!=4 || s==0) ? bias[gc] : 0.f;
#pragma unroll
      for (int r=0;r<4;r++){
        const int gr = gr0 + r;
        float v = acc[i][j][r] + bv;
        if constexpr (MODE==1) v = gelu_f(v);
        if constexpr (MODE==3) v *= scale;
        if constexpr (MODE==4){
          ((bf16*)C)[((size_t)s*4096 + gr)*N + gc] = __float2bfloat16(v);
        } else {
          ((bf16*)C)[(size_t)gr*N + gc] = __float2bfloat16(v);
        }
      }
    }
  }
}

// ---------------- fused split-K reduce + residual + LayerNorm ----------------
template<int OUTF32, int WRITEX>
__global__ __launch_bounds__(256)
void ln_red(const float* __restrict__ base, unsigned bmask,
            const bf16* __restrict__ part, int ks,
            const float* __restrict__ g, const float* __restrict__ b,
            float* __restrict__ xw, void* __restrict__ out)
{
  const int row  = blockIdx.x*4 + (threadIdx.x>>6);
  const int lane = threadIdx.x & 63;
  const float2* br = (const float2*)base + (size_t)(row & bmask)*576;
  float2 v[9];
#pragma unroll
  for (int r=0;r<9;r++) v[r] = br[r*64+lane];
  for (int s=0;s<ks;s++){
    const __hip_bfloat162* pr = (const __hip_bfloat162*)part + ((size_t)s*4096 + row)*576;
#pragma unroll
    for (int r=0;r<9;r++){
      const float2 pv = __bfloat1622float2(pr[r*64+lane]);
      v[r].x += pv.x; v[r].y += pv.y;
    }
  }
  float sm=0.f, ss=0.f;
#pragma unroll
  for (int r=0;r<9;r++){
    sm += v[r].x + v[r].y;
    ss += v[r].x*v[r].x + v[r].y*v[r].y;
  }
#pragma unroll
  for (int m=1;m<64;m<<=1){ sm += __shfl_xor(sm,m,64); ss += __shfl_xor(ss,m,64); }
  const float mean = sm*(1.0f/1152.0f);
  const float rs = rsqrtf(ss*(1.0f/1152.0f) - mean*mean + 1e-6f);
  const float2* gr2 = (const float2*)g;
  const float2* br2 = (const float2*)b;
#pragma unroll
  for (int r=0;r<9;r++){
    const int c = r*64+lane;
    if constexpr (WRITEX) ((float2*)xw)[(size_t)row*576 + c] = v[r];
    const float2 gg = gr2[c], bb = br2[c];
    const float o0 = (v[r].x-mean)*rs*gg.x + bb.x;
    const float o1 = (v[r].y-mean)*rs*gg.y + bb.y;
    if constexpr (OUTF32){
      ((float2*)out)[(size_t)row*576 + c] = make_float2(o0, o1);
    } else {
      __hip_bfloat162 hv;
      hv.x = __float2bfloat16(o0); hv.y = __float2bfloat16(o1);
      ((__hip_bfloat162*)out)[(size_t)row*576 + c] = hv;
    }
  }
}

// ---------------- im2col for 14x14 stride-14 conv: [4096, 608] bf16 ----
__global__ __launch_bounds__(256)
void im2col_kernel(const float* __restrict__ img, bf16* __restrict__ out)
{
  const int idx = blockIdx.x*256 + threadIdx.x;  // 4096*608
  const int kk = idx % 608;
  const int rr = idx / 608;
  float v = 0.f;
  if (kk < 588){
    const int bt = rr >> 10, n = rr & 1023;
    const int py = n >> 5, px = n & 31;
    const int ph = kk / 42;
    const int rem = kk - ph*42;
    const int pw = rem / 3;
    const int c  = rem - pw*3;
    v = img[(((size_t)bt*448 + py*14 + ph)*448 + px*14 + pw)*3 + c];
  }
  out[idx] = __float2bfloat16(v);
}

// ---------------- fp32 [K,N] -> bf16 [Np,Kp] transpose+convert, zero-pad -----------------
__global__ __launch_bounds__(256)
void transpose_cvt(const float* __restrict__ in, bf16* __restrict__ out,
                   int K, int N, int Kp, int Np)
{
  __shared__ float tile[32][33];
  const int nt = blockIdx.x*32, kt = blockIdx.y*32;
  const int r = threadIdx.x>>5, c = threadIdx.x&31;
#pragma unroll
  for (int i=0;i<4;i++){
    const int k = kt + r + i*8, n = nt + c;
    tile[r+i*8][c] = (k<K && n<N) ? in[(size_t)k*N + n] : 0.f;
  }
  __syncthreads();
#pragma unroll
  for (int i=0;i<4;i++){
    const int n = nt + r + i*8, k = kt + c;
    out[(size_t)n*Kp + k] = __float2bfloat16(tile[c][r+i*8]);
  }
}

// ---------------- bias packing + zero-buffer init ---------------
__global__ __launch_bounds__(256)
void pack_biases(const float* __restrict__ bq, const float* __restrict__ bk,
                 const float* __restrict__ bv, const float* __restrict__ b1,
                 int l, float* __restrict__ bqkv, float* __restrict__ b1p,
                 float4* __restrict__ zbuf)
{
  const int i = blockIdx.x*256 + threadIdx.x;
  if (i < 3456){
    float v;
    if (i < 1152)      v = bq[l*1152 + i];
    else if (i < 2304) v = bk[l*1152 + i - 1152];
    else               v = bv[l*1152 + i - 2304];
    bqkv[i] = v;
  }
  if (i < 4352) b1p[i] = (i < 4304) ? b1[l*4304 + i] : 0.f;
  if (i == 0) *zbuf = make_float4(0.f,0.f,0.f,0.f);
}

// -------- v repack transposed: qkv v-cols -> [64 bh][80 dh][1024 n] ------
// pad rows: dh==72 set to ONES (accumulates the softmax denominator in PV),
// dh>72 zero.
__global__ __launch_bounds__(256)
void transpose_v(const bf16* __restrict__ src, bf16* __restrict__ dst)
{
  __shared__ bf16 tile[128][73];
  const int nc = blockIdx.x, bh = blockIdx.y;
  const int bt = bh>>4, hh = bh&15;
  const bf16* s = src + ((size_t)bt*1024 + nc*128)*3456 + 2304 + hh*72;
  for (int e=threadIdx.x; e<128*72; e+=256){
    const int n = e/72, dh = e - n*72;
    tile[n][dh] = s[(size_t)n*3456 + dh];
  }
  __syncthreads();
  bf16* d = dst + (size_t)bh*80*1024 + nc*128;
  const bf16 z  = __float2bfloat16(0.f);
  const bf16 on = __float2bfloat16(1.f);
  for (int e=threadIdx.x; e<80*128; e+=256){
    const int dh = e>>7, n = e&127;
    d[(size_t)dh*1024 + n] = (dh<72) ? tile[n][dh] : (dh==72 ? on : z);
  }
}

// ---------------- flash attention v2: swapped QK^T, lane-local softmax ------
__global__ __launch_bounds__(256,3)
void attn_kernel(const bf16* __restrict__ qkv, const bf16* __restrict__ vb,
                 const float4* __restrict__ zbuf, bf16* __restrict__ outp)
{
  __shared__ bf16 Ks[128*96];   // 24576 B; first 16KB aliased as P-buffer after QK
  __shared__ bf16 Vs[80*128];   // 20480 B
  const int tid = threadIdx.x, wave = tid>>6, lane = tid&63;
  const int quad = lane>>4, l16 = lane&15;
  // T1: XCD-chunked swizzle
  int lid = blockIdx.x + (blockIdx.y<<4);
  lid = ((lid & 7) << 7) + (lid >> 3);
  const int bh = lid >> 4, q0 = (lid & 15) << 6;
  const int bt = bh>>4, hh = bh&15;
  const bf16* vg = vb + (size_t)bh*80*1024;
  bf16x8 af0{}, af1{}, af2{};
  {
    const bf16* qp = qkv + (size_t)(bt*1024 + q0 + wave*16 + l16)*3456 + hh*72 + quad*8;
    af0 = *(const bf16x8*)(qp);
    af1 = *(const bf16x8*)(qp+32);
    if (quad==0) af2 = *(const bf16x8*)(qp+64);
  }
  float mr = -3.0e38f;          // running row-max for q = wave*16+l16 (uniform over quad)
  floatx4 oacc[5] = {};
  const int prow = wave*16 + l16;
  const int hi2 = (l16>>2)&3, lo2 = l16&3;
  char* const psrow = (char*)Ks + prow*256;

  for (int kc=0;kc<8;kc++){
    __syncthreads();   // (A) everyone done with PV reads of Ps/Vs from prev iter
    {
      const char* kcb = (const char*)(qkv + (size_t)(bt*1024 + kc*128)*3456 + 1152 + hh*72);
#pragma unroll
      for (int i=0;i<6;i++){
        const int u = (wave*6+i)*64 + lane;      // 0..1535
        const int row = u/12;
        const int pp = u - row*12;
        const int c = (pp & 12) | ((pp & 3) ^ (row & 3));
        const void* src = (c<9) ? (const void*)(kcb + (size_t)row*6912 + c*16)
                                : (const void*)zbuf;
        gl_lds16(src, (char*)Ks + (size_t)(wave*6+i)*1024);
      }
#pragma unroll
      for (int i=0;i<5;i++){
        const int u = (wave*5+i)*64 + lane;      // 0..1279
        const int row = u>>4;
        const int pp = u & 15;
        const int c = (pp & 8) | ((pp & 7) ^ (row & 7));
        gl_lds16((const char*)vg + (size_t)row*2048 + kc*256 + c*16,
                 (char*)Vs + (size_t)(wave*5+i)*1024);
      }
    }
    __syncthreads();   // (B) tiles staged
    floatx4 sc[8] = {};
    const int ksw = (quad ^ (l16&3))*8;
#pragma unroll
    for (int ct=0;ct<8;ct++){
      const bf16* kr = Ks + (ct*16+l16)*96 + ksw;
      sc[ct] = __builtin_amdgcn_mfma_f32_16x16x32_bf16(*(const bf16x8*)(kr   ), af0, sc[ct],0,0,0);
      sc[ct] = __builtin_amdgcn_mfma_f32_16x16x32_bf16(*(const bf16x8*)(kr+32), af1, sc[ct],0,0,0);
      sc[ct] = __builtin_amdgcn_mfma_f32_16x16x32_bf16(*(const bf16x8*)(kr+64), af2, sc[ct],0,0,0);
    }
    // row-max: local over 32 values, then combine quads (lane^16, lane^32)
    float cm = sc[0][0];
#pragma unroll
    for (int ct=0;ct<8;ct++)
#pragma unroll
      for (int r=0;r<4;r++) cm = fmaxf(cm, sc[ct][r]);
    cm = fmaxf(cm, __shfl_xor(cm, 16, 64));
    cm = fmaxf(cm, __shfl_xor(cm, 32, 64));
    // T13 defer-max
    if (!__all(cm <= mr + 8.0f)){
      const float mn = fmaxf(mr, cm);
      const float alv = exp2f(mr - mn);   // 0 on first iteration
      mr = mn;
      float alb[4];
#pragma unroll
      for (int r=0;r<4;r++) alb[r] = __shfl(alv, quad*4 + r, 64);
#pragma unroll
      for (int t=0;t<5;t++)
#pragma unroll
        for (int r=0;r<4;r++) oacc[t][r] *= alb[r];
    }
    __syncthreads();   // (C) all waves done reading Ks -> safe to write P into alias
    // P = exp2(sc - mr) -> bf16, one swizzled b64 write per ct (k quad*4..+3)
#pragma unroll
    for (int ct=0;ct<8;ct++){
      bf16x4 pk;
      pk[0] = (__bf16)exp2f(sc[ct][0] - mr);
      pk[1] = (__bf16)exp2f(sc[ct][1] - mr);
      pk[2] = (__bf16)exp2f(sc[ct][2] - mr);
      pk[3] = (__bf16)exp2f(sc[ct][3] - mr);
      *(bf16x4*)(psrow + (((ct^hi2)<<5) | ((quad^lo2)<<3))) = pk;
    }
    // PV: rebuild A-fragments from the swizzled P-buffer (2x b64 per ks)
#pragma unroll
    for (int ks=0;ks<4;ks++){
      const int ct0 = 2*ks + (quad>>1);
      const int g0 = (quad&1)*2;
      const bf16x4 plo = *(const bf16x4*)(psrow + (((ct0^hi2)<<5) | (((g0  )^lo2)<<3)));
      const bf16x4 phi = *(const bf16x4*)(psrow + (((ct0^hi2)<<5) | (((g0+1)^lo2)<<3)));
      bf16x8 pf;
      pf[0]=plo[0]; pf[1]=plo[1]; pf[2]=plo[2]; pf[3]=plo[3];
      pf[4]=phi[0]; pf[5]=phi[1]; pf[6]=phi[2]; pf[7]=phi[3];
      const int c = ks*4 + quad;
      const int pp = (c & 8) | ((c & 7) ^ (l16 & 7));
#pragma unroll
      for (int t=0;t<5;t++){
        const bf16x8 vf = *(const bf16x8*)(Vs + (t*16+l16)*128 + pp*8);
        oacc[t] = __builtin_amdgcn_mfma_f32_16x16x32_bf16(pf, vf, oacc[t],0,0,0);
      }
    }
  }
  // denominator lives in oacc[4][r] at lanes l16==8 (dh==72 ones-row)
  float inv[4];
#pragma unroll
  for (int r=0;r<4;r++){
    const float lr = __shfl(oacc[4][r], quad*16 + 8, 64);
    inv[r] = 1.0f / lr;
  }
#pragma unroll
  for (int t=0;t<5;t++){
    const int dh = t*16+l16;
    if (dh < 72){
#pragma unroll
      for (int r=0;r<4;r++){
        const int q = wave*16 + quad*4 + r;
        const float v = oacc[t][r] * inv[r];
        outp[((size_t)bt*1024 + q0 + q)*1152 + hh*72 + dh] = __float2bfloat16(v);
      }
    }
  }
}

extern "C" void kernel_launch(void* const* d_in, const int* in_sizes, int n_in,
                              void* d_out, int out_size, void* d_ws, size_t ws_size,
                              hipStream_t stream)
{
  (void)in_sizes; (void)n_in; (void)out_size; (void)ws_size;
  const float* images = (const float*)d_in[0];
  const float* conv_w = (const float*)d_in[1];
  const float* conv_b = (const float*)d_in[2];
  const float* pos_emb= (const float*)d_in[3];
  const float* ln1_g  = (const float*)d_in[4];
  const float* ln1_b  = (const float*)d_in[5];
  const float* Wq     = (const float*)d_in[6];
  const float* bq     = (const float*)d_in[7];
  const float* Wk     = (const float*)d_in[8];
  const float* bk     = (const float*)d_in[9];
  const float* Wv     = (const float*)d_in[10];
  const float* bv     = (const float*)d_in[11];
  const float* Wo     = (const float*)d_in[12];
  const float* bo     = (const float*)d_in[13];
  const float* ln2_g  = (const float*)d_in[14];
  const float* ln2_b  = (const float*)d_in[15];
  const float* W1     = (const float*)d_in[16];
  const float* b1     = (const float*)d_in[17];
  const float* W2     = (const float*)d_in[18];
  const float* b2     = (const float*)d_in[19];
  const float* lnf_g  = (const float*)d_in[20];
  const float* lnf_b  = (const float*)d_in[21];

  char* p = (char*)d_ws;
  auto take = [&](size_t nbytes)->char*{ char* q = p; p += (nbytes + 255) & ~(size_t)255; return q; };
  float* xw   = (float*)take(4096ull*1152*4);
  bf16* hbuf  = (bf16*) take(4096ull*1152*2);
  bf16* h1    = (bf16*) take(4096ull*4352*2);
  bf16* qkvr  = h1;
  bf16* vbuf  = (bf16*) take(64ull*80*1024*2);
  bf16* imcol = vbuf;
  bf16* aout  = (bf16*) take(4096ull*1152*2);
  bf16* WqkvT = (bf16*) take(3456ull*1152*2);
  bf16* WoT   = (bf16*) take(1152ull*1152*2);
  bf16* W1T   = (bf16*) take(4352ull*1152*2);
  bf16* cwT   = W1T;
  bf16* W2T   = (bf16*) take(1152ull*4352*2);
  bf16* Ppart = (bf16*) take(4ull*4096*1152*2);  // bf16 split-K partials (max ks=4)
  float* bqkv = (float*)take(3456*4);
  float* b1p  = (float*)take(4352*4);
  float4* zbuf= (float4*)take(256);

  const float qscale = 1.4426950408889634f / sqrtf(72.0f);

  im2col_kernel<<<9728, 256, 0, stream>>>(images, imcol);
  transpose_cvt<<<dim3(36,19), 256, 0, stream>>>(conv_w, cwT, 588, 1152, 608, 1152);
  gemm_bf16<4><<<dim3(9,32,2), 256, 0, stream>>>(imcol, cwT, conv_b, Ppart, 1152, 608, 320, 0.f);

  for (int l=0;l<4;l++){
    transpose_cvt<<<dim3(36,36), 256, 0, stream>>>(Wq + (size_t)l*1152*1152, WqkvT,                1152,1152,1152,1152);
    transpose_cvt<<<dim3(36,36), 256, 0, stream>>>(Wk + (size_t)l*1152*1152, WqkvT + 1152ull*1152, 1152,1152,1152,1152);
    transpose_cvt<<<dim3(36,36), 256, 0, stream>>>(Wv + (size_t)l*1152*1152, WqkvT + 2304ull*1152, 1152,1152,1152,1152);
    transpose_cvt<<<dim3(36,36), 256, 0, stream>>>(Wo + (size_t)l*1152*1152, WoT, 1152,1152,1152,1152);
    transpose_cvt<<<dim3(136,36),256, 0, stream>>>(W1 + (size_t)l*1152*4304, W1T, 1152,4304,1152,4352);
    transpose_cvt<<<dim3(36,136),256, 0, stream>>>(W2 + (size_t)l*4304*1152, W2T, 4304,1152,4352,1152);
    pack_biases<<<17,256,0,stream>>>(bq,bk,bv,b1,l,bqkv,b1p,zbuf);

    if (l==0)
      ln_red<0,1><<<1024,256,0,stream>>>(pos_emb, 1023u, Ppart, 2, ln1_g, ln1_b, xw, hbuf);
    else
      ln_red<0,1><<<1024,256,0,stream>>>(xw, 4095u, Ppart, 4, ln1_g + l*1152, ln1_b + l*1152, xw, hbuf);

    gemm_bf16<3><<<dim3(27,32,1),256,0,stream>>>(hbuf, WqkvT, bqkv, qkvr, 3456, 1152, 1152, qscale);
    transpose_v<<<dim3(8,64),256,0,stream>>>(qkvr, vbuf);
    attn_kernel<<<dim3(16,64),256,0,stream>>>(qkvr, vbuf, zbuf, aout);
    gemm_bf16<4><<<dim3(9,32,3),256,0,stream>>>(aout, WoT, bo + l*1152, Ppart, 1152, 1152, 384, 0.f);
    ln_red<0,1><<<1024,256,0,stream>>>(xw, 4095u, Ppart, 3, ln2_g + l*1152, ln2_b + l*1152, xw, hbuf);

    gemm_bf16<1><<<dim3(34,32,1),256,0,stream>>>(hbuf, W1T, b1p, h1, 4352, 1152, 1152, 0.f);
    gemm_bf16<4><<<dim3(9,32,4),256,0,stream>>>(h1, W2T, b2 + l*1152, Ppart, 1152, 4352, 1088, 0.f);
  }
  ln_red<1,0><<<1024,256,0,stream>>>(xw, 4095u, Ppart, 4, lnf_g, lnf_b, nullptr, (float*)d_out);
}

// Round 9
// 1447.792 us; speedup vs baseline: 1.0624x; 1.0080x over previous
//
#include <hip/hip_runtime.h>
#include <hip/hip_bf16.h>
#include <stdint.h>
#include <math.h>

typedef __hip_bfloat16 bf16;
typedef __attribute__((ext_vector_type(4))) float floatx4;
typedef __attribute__((ext_vector_type(8))) __bf16 bf16x8;
typedef __attribute__((ext_vector_type(4))) __bf16 bf16x4;

typedef __attribute__((address_space(1))) void gvoid_t;
typedef __attribute__((address_space(3))) void lvoid_t;

__device__ __forceinline__ void gl_lds16(const void* g, void* l){
  __builtin_amdgcn_global_load_lds((gvoid_t*)g, (lvoid_t*)l, 16, 0, 0);
}

__device__ __forceinline__ float gelu_f(float v){
  float u = 0.7978845608028654f*(v + 0.044715f*v*v*v);
  float e = __expf(2.0f*u);
  return v*(1.0f - 1.0f/(e+1.0f));
}

// ---------------- GEMM: C[M,N] = A[M,K](bf16) @ BT[N,K](bf16) + bias ----------
// MODE 0: bf16 C = acc+bias
// MODE 1: bf16 C = gelu(acc+bias)
// MODE 3: bf16 C = (acc+bias) * (n0<1152 ? qs : 1)   [QKV with folded q-scale]
// MODE 4: bf16 partial C[s][M][N] = acc + (s==0 ? bias : 0)   [split-K, blockIdx.z = s]
//
// R9: ring-3 128x128 (R8 structure, verified) with the K-loop UNROLLED BY 3 so
// buffer indices are compile-time: every ds_read = fixed VGPR addr + immediate
// offset (BUF*16384+i*1024), stage dests are constants, global stage addrs are
// two running pointers (+64B/step). Removes the ~350cy/block-iter of VALU
// addressing R8's counters showed (VALUBusy 33% ~ LDS ~ MFMA, serialized).
template<int MODE>
__global__ __launch_bounds__(256,3)
void gemm_bf16(const bf16* __restrict__ A, const bf16* __restrict__ BT,
               const float* __restrict__ bias, void* __restrict__ C,
               int N, int K, int kc, float qs)
{
  __shared__ __align__(128) char ldsm[49152];   // 3 x 16384
  const int tid  = threadIdx.x;
  const int wave = tid>>6, lane = tid&63;
  const int quad = lane>>4, l16 = lane&15;

  // ---- T1: bijective XCD-chunked swizzle + GROUP_M=4 m-fastest traversal ----
  // all grids here have nwg % 8 == 0 and gridDim.y % 4 == 0
  int bm, bn;
  {
    const int nx = gridDim.x;
    const int nwg = nx * gridDim.y;
    int lid = blockIdx.x + nx*blockIdx.y;
    const int q = nwg >> 3;
    const int xcd = lid & 7, off = lid >> 3;
    lid = xcd*q + off;                  // contiguous chunk per XCD
    const int per = nx << 2;            // blocks per 4-row m-group
    const int g   = lid / per;
    const int rem = lid - g*per;
    bm = (g<<2) + (rem & 3);            // m fastest within quad -> A-quad L2-resident
    bn = rem >> 2;                      // n outer -> B panel streams with 4x reuse
  }
  const int m0 = bm*128, n0 = bn*128;

  const int s  = blockIdx.z;
  const int kb = s*kc;
  const int ke = min(K, kb + kc);
  const int T  = (ke - kb) >> 5;        // all chunks are multiples of 32
  const int wm = (wave&1)*64, wn = (wave>>1)*64;
  floatx4 acc[4][4] = {};

  // ---- staging addresses (pre-swizzled global source) ----
  // thread t covers rows (t>>2) and (t>>2)+64, 16B slot (t&3) holding
  // LOGICAL slot (t&3)^(row&3)
  const int grow  = tid>>2;
  const int gslot = (tid&3) ^ (grow&3);
  const bf16* aBase = A  + (size_t)(m0 + grow)*K + kb + gslot*8;
  const bf16* bBase = BT + (size_t)(n0 + grow)*K + kb + gslot*8;
  const size_t rowK64 = (size_t)64*K;
  char* ldw = ldsm + (wave<<10);

  // ---- swizzled ds_read offsets: byte = row*64 + ((quad^(row&3))*16), row&3==l16&3 ----
  const int swz = (quad ^ (l16&3))<<4;
  const int aRd = ((wm + l16)<<6) + swz;           // A region at +0    (8KB, 128 rows)
  const int bRd = 8192 + ((wn + l16)<<6) + swz;    // B region at +8192 (8KB, 128 rows)

  // prologue: tiles 0,1 in flight (8 loads)
  {
    gl_lds16(aBase,          ldw);
    gl_lds16(aBase + rowK64, ldw + 4096);
    gl_lds16(bBase,          ldw + 8192);
    gl_lds16(bBase + rowK64, ldw + 12288);
    gl_lds16(aBase + 32,          ldw + 16384);
    gl_lds16(aBase + 32 + rowK64, ldw + 16384 + 4096);
    gl_lds16(bBase + 32,          ldw + 16384 + 8192);
    gl_lds16(bBase + 32 + rowK64, ldw + 16384 + 12288);
  }
  const bf16* pA = aBase + 64;   // next tile (t+2) global source, +32 elems/step
  const bf16* pB = bBase + 64;

#define STEP(BUF, TT)                                                            \
  {                                                                              \
    if ((TT) == T-1) asm volatile("s_waitcnt vmcnt(0)" ::: "memory");            \
    else             asm volatile("s_waitcnt vmcnt(4)" ::: "memory");            \
    asm volatile("s_barrier" ::: "memory");                                      \
    bf16x8 af[4], bfr[4];                                                        \
    _Pragma("unroll")                                                            \
    for (int i=0;i<4;i++)                                                        \
      af[i]  = *(const bf16x8*)(ldsm + (BUF)*16384 + aRd + (i<<10));             \
    _Pragma("unroll")                                                            \
    for (int j=0;j<4;j++)                                                        \
      bfr[j] = *(const bf16x8*)(ldsm + (BUF)*16384 + bRd + (j<<10));             \
    if ((TT)+2 < T){                                                             \
      char* ld = ldw + (((BUF)+2)%3)*16384;                                      \
      gl_lds16(pA,          ld);                                                 \
      gl_lds16(pA + rowK64, ld + 4096);                                          \
      gl_lds16(pB,          ld + 8192);                                          \
      gl_lds16(pB + rowK64, ld + 12288);                                         \
      pA += 32; pB += 32;                                                        \
    }                                                                            \
    __builtin_amdgcn_s_setprio(1);                                               \
    _Pragma("unroll")                                                            \
    for (int i=0;i<4;i++)                                                        \
      _Pragma("unroll")                                                          \
      for (int j=0;j<4;j++)                                                      \
        acc[i][j] = __builtin_amdgcn_mfma_f32_16x16x32_bf16(af[i], bfr[j],       \
                                                            acc[i][j], 0,0,0);   \
    __builtin_amdgcn_s_setprio(0);                                               \
  }

  int t = 0;
  for (; t+3 <= T; t += 3){
    STEP(0, t)
    STEP(1, t+1)
    STEP(2, t+2)
  }
  if (t < T)   STEP(0, t)
  if (t+1 < T) STEP(1, t+1)
#undef STEP

  const float scale = (MODE==3 && n0<1152) ? qs : 1.0f;
#pragma unroll
  for (int i=0;i<4;i++){
    const int gr0 = m0 + wm + i*16 + quad*4;
#pragma unroll
    for (int j=0;j<4;j++){
      const int gc = n0 + wn + j*16 + l16;
      const float bv = (MODE!=4 || s==0) ? bias[gc] : 0.f;
#pragma unroll
      for (int r=0;r<4;r++){
        const int gr = gr0 + r;
        float v = acc[i][j][r] + bv;
        if constexpr (MODE==1) v = gelu_f(v);
        if constexpr (MODE==3) v *= scale;
        if constexpr (MODE==4){
          ((bf16*)C)[((size_t)s*4096 + gr)*N + gc] = __float2bfloat16(v);
        } else {
          ((bf16*)C)[(size_t)gr*N + gc] = __float2bfloat16(v);
        }
      }
    }
  }
}

// ---------------- fused split-K reduce + residual + LayerNorm ----------------
template<int OUTF32, int WRITEX>
__global__ __launch_bounds__(256)
void ln_red(const float* __restrict__ base, unsigned bmask,
            const bf16* __restrict__ part, int ks,
            const float* __restrict__ g, const float* __restrict__ b,
            float* __restrict__ xw, void* __restrict__ out)
{
  const int row  = blockIdx.x*4 + (threadIdx.x>>6);
  const int lane = threadIdx.x & 63;
  const float2* br = (const float2*)base + (size_t)(row & bmask)*576;
  float2 v[9];
#pragma unroll
  for (int r=0;r<9;r++) v[r] = br[r*64+lane];
  for (int s=0;s<ks;s++){
    const __hip_bfloat162* pr = (const __hip_bfloat162*)part + ((size_t)s*4096 + row)*576;
#pragma unroll
    for (int r=0;r<9;r++){
      const float2 pv = __bfloat1622float2(pr[r*64+lane]);
      v[r].x += pv.x; v[r].y += pv.y;
    }
  }
  float sm=0.f, ss=0.f;
#pragma unroll
  for (int r=0;r<9;r++){
    sm += v[r].x + v[r].y;
    ss += v[r].x*v[r].x + v[r].y*v[r].y;
  }
#pragma unroll
  for (int m=1;m<64;m<<=1){ sm += __shfl_xor(sm,m,64); ss += __shfl_xor(ss,m,64); }
  const float mean = sm*(1.0f/1152.0f);
  const float rs = rsqrtf(ss*(1.0f/1152.0f) - mean*mean + 1e-6f);
  const float2* gr2 = (const float2*)g;
  const float2* br2 = (const float2*)b;
#pragma unroll
  for (int r=0;r<9;r++){
    const int c = r*64+lane;
    if constexpr (WRITEX) ((float2*)xw)[(size_t)row*576 + c] = v[r];
    const float2 gg = gr2[c], bb = br2[c];
    const float o0 = (v[r].x-mean)*rs*gg.x + bb.x;
    const float o1 = (v[r].y-mean)*rs*gg.y + bb.y;
    if constexpr (OUTF32){
      ((float2*)out)[(size_t)row*576 + c] = make_float2(o0, o1);
    } else {
      __hip_bfloat162 hv;
      hv.x = __float2bfloat16(o0); hv.y = __float2bfloat16(o1);
      ((__hip_bfloat162*)out)[(size_t)row*576 + c] = hv;
    }
  }
}

// ---------------- im2col for 14x14 stride-14 conv: [4096, 608] bf16 ----
__global__ __launch_bounds__(256)
void im2col_kernel(const float* __restrict__ img, bf16* __restrict__ out)
{
  const int idx = blockIdx.x*256 + threadIdx.x;  // 4096*608
  const int kk = idx % 608;
  const int rr = idx / 608;
  float v = 0.f;
  if (kk < 588){
    const int bt = rr >> 10, n = rr & 1023;
    const int py = n >> 5, px = n & 31;
    const int ph = kk / 42;
    const int rem = kk - ph*42;
    const int pw = rem / 3;
    const int c  = rem - pw*3;
    v = img[(((size_t)bt*448 + py*14 + ph)*448 + px*14 + pw)*3 + c];
  }
  out[idx] = __float2bfloat16(v);
}

// ---------------- fp32 [K,N] -> bf16 [Np,Kp] transpose+convert, zero-pad -----------------
__global__ __launch_bounds__(256)
void transpose_cvt(const float* __restrict__ in, bf16* __restrict__ out,
                   int K, int N, int Kp, int Np)
{
  __shared__ float tile[32][33];
  const int nt = blockIdx.x*32, kt = blockIdx.y*32;
  const int r = threadIdx.x>>5, c = threadIdx.x&31;
#pragma unroll
  for (int i=0;i<4;i++){
    const int k = kt + r + i*8, n = nt + c;
    tile[r+i*8][c] = (k<K && n<N) ? in[(size_t)k*N + n] : 0.f;
  }
  __syncthreads();
#pragma unroll
  for (int i=0;i<4;i++){
    const int n = nt + r + i*8, k = kt + c;
    out[(size_t)n*Kp + k] = __float2bfloat16(tile[c][r+i*8]);
  }
}

// ---------------- bias packing + zero-buffer init ---------------
__global__ __launch_bounds__(256)
void pack_biases(const float* __restrict__ bq, const float* __restrict__ bk,
                 const float* __restrict__ bv, const float* __restrict__ b1,
                 int l, float* __restrict__ bqkv, float* __restrict__ b1p,
                 float4* __restrict__ zbuf)
{
  const int i = blockIdx.x*256 + threadIdx.x;
  if (i < 3456){
    float v;
    if (i < 1152)      v = bq[l*1152 + i];
    else if (i < 2304) v = bk[l*1152 + i - 1152];
    else               v = bv[l*1152 + i - 2304];
    bqkv[i] = v;
  }
  if (i < 4352) b1p[i] = (i < 4304) ? b1[l*4304 + i] : 0.f;
  if (i == 0) *zbuf = make_float4(0.f,0.f,0.f,0.f);
}

// -------- v repack transposed: qkv v-cols -> [64 bh][80 dh][1024 n] ------
// pad rows: dh==72 set to ONES (accumulates the softmax denominator in PV),
// dh>72 zero.
__global__ __launch_bounds__(256)
void transpose_v(const bf16* __restrict__ src, bf16* __restrict__ dst)
{
  __shared__ bf16 tile[128][73];
  const int nc = blockIdx.x, bh = blockIdx.y;
  const int bt = bh>>4, hh = bh&15;
  const bf16* s = src + ((size_t)bt*1024 + nc*128)*3456 + 2304 + hh*72;
  for (int e=threadIdx.x; e<128*72; e+=256){
    const int n = e/72, dh = e - n*72;
    tile[n][dh] = s[(size_t)n*3456 + dh];
  }
  __syncthreads();
  bf16* d = dst + (size_t)bh*80*1024 + nc*128;
  const bf16 z  = __float2bfloat16(0.f);
  const bf16 on = __float2bfloat16(1.f);
  for (int e=threadIdx.x; e<80*128; e+=256){
    const int dh = e>>7, n = e&127;
    d[(size_t)dh*1024 + n] = (dh<72) ? tile[n][dh] : (dh==72 ? on : z);
  }
}

// ---------------- flash attention v2: swapped QK^T, lane-local softmax ------
__global__ __launch_bounds__(256,3)
void attn_kernel(const bf16* __restrict__ qkv, const bf16* __restrict__ vb,
                 const float4* __restrict__ zbuf, bf16* __restrict__ outp)
{
  __shared__ bf16 Ks[128*96];   // 24576 B; first 16KB aliased as P-buffer after QK
  __shared__ bf16 Vs[80*128];   // 20480 B
  const int tid = threadIdx.x, wave = tid>>6, lane = tid&63;
  const int quad = lane>>4, l16 = lane&15;
  // T1: XCD-chunked swizzle
  int lid = blockIdx.x + (blockIdx.y<<4);
  lid = ((lid & 7) << 7) + (lid >> 3);
  const int bh = lid >> 4, q0 = (lid & 15) << 6;
  const int bt = bh>>4, hh = bh&15;
  const bf16* vg = vb + (size_t)bh*80*1024;
  bf16x8 af0{}, af1{}, af2{};
  {
    const bf16* qp = qkv + (size_t)(bt*1024 + q0 + wave*16 + l16)*3456 + hh*72 + quad*8;
    af0 = *(const bf16x8*)(qp);
    af1 = *(const bf16x8*)(qp+32);
    if (quad==0) af2 = *(const bf16x8*)(qp+64);
  }
  float mr = -3.0e38f;          // running row-max for q = wave*16+l16 (uniform over quad)
  floatx4 oacc[5] = {};
  const int prow = wave*16 + l16;
  const int hi2 = (l16>>2)&3, lo2 = l16&3;
  char* const psrow = (char*)Ks + prow*256;

  for (int kc=0;kc<8;kc++){
    __syncthreads();   // (A) everyone done with PV reads of Ps/Vs from prev iter
    {
      const char* kcb = (const char*)(qkv + (size_t)(bt*1024 + kc*128)*3456 + 1152 + hh*72);
#pragma unroll
      for (int i=0;i<6;i++){
        const int u = (wave*6+i)*64 + lane;      // 0..1535
        const int row = u/12;
        const int pp = u - row*12;
        const int c = (pp & 12) | ((pp & 3) ^ (row & 3));
        const void* src = (c<9) ? (const void*)(kcb + (size_t)row*6912 + c*16)
                                : (const void*)zbuf;
        gl_lds16(src, (char*)Ks + (size_t)(wave*6+i)*1024);
      }
#pragma unroll
      for (int i=0;i<5;i++){
        const int u = (wave*5+i)*64 + lane;      // 0..1279
        const int row = u>>4;
        const int pp = u & 15;
        const int c = (pp & 8) | ((pp & 7) ^ (row & 7));
        gl_lds16((const char*)vg + (size_t)row*2048 + kc*256 + c*16,
                 (char*)Vs + (size_t)(wave*5+i)*1024);
      }
    }
    __syncthreads();   // (B) tiles staged
    floatx4 sc[8] = {};
    const int ksw = (quad ^ (l16&3))*8;
#pragma unroll
    for (int ct=0;ct<8;ct++){
      const bf16* kr = Ks + (ct*16+l16)*96 + ksw;
      sc[ct] = __builtin_amdgcn_mfma_f32_16x16x32_bf16(*(const bf16x8*)(kr   ), af0, sc[ct],0,0,0);
      sc[ct] = __builtin_amdgcn_mfma_f32_16x16x32_bf16(*(const bf16x8*)(kr+32), af1, sc[ct],0,0,0);
      sc[ct] = __builtin_amdgcn_mfma_f32_16x16x32_bf16(*(const bf16x8*)(kr+64), af2, sc[ct],0,0,0);
    }
    // row-max: local over 32 values, then combine quads (lane^16, lane^32)
    float cm = sc[0][0];
#pragma unroll
    for (int ct=0;ct<8;ct++)
#pragma unroll
      for (int r=0;r<4;r++) cm = fmaxf(cm, sc[ct][r]);
    cm = fmaxf(cm, __shfl_xor(cm, 16, 64));
    cm = fmaxf(cm, __shfl_xor(cm, 32, 64));
    // T13 defer-max
    if (!__all(cm <= mr + 8.0f)){
      const float mn = fmaxf(mr, cm);
      const float alv = exp2f(mr - mn);   // 0 on first iteration
      mr = mn;
      float alb[4];
#pragma unroll
      for (int r=0;r<4;r++) alb[r] = __shfl(alv, quad*4 + r, 64);
#pragma unroll
      for (int t=0;t<5;t++)
#pragma unroll
        for (int r=0;r<4;r++) oacc[t][r] *= alb[r];
    }
    __syncthreads();   // (C) all waves done reading Ks -> safe to write P into alias
    // P = exp2(sc - mr) -> bf16, one swizzled b64 write per ct (k quad*4..+3)
#pragma unroll
    for (int ct=0;ct<8;ct++){
      bf16x4 pk;
      pk[0] = (__bf16)exp2f(sc[ct][0] - mr);
      pk[1] = (__bf16)exp2f(sc[ct][1] - mr);
      pk[2] = (__bf16)exp2f(sc[ct][2] - mr);
      pk[3] = (__bf16)exp2f(sc[ct][3] - mr);
      *(bf16x4*)(psrow + (((ct^hi2)<<5) | ((quad^lo2)<<3))) = pk;
    }
    // PV: rebuild A-fragments from the swizzled P-buffer (2x b64 per ks)
#pragma unroll
    for (int ks=0;ks<4;ks++){
      const int ct0 = 2*ks + (quad>>1);
      const int g0 = (quad&1)*2;
      const bf16x4 plo = *(const bf16x4*)(psrow + (((ct0^hi2)<<5) | (((g0  )^lo2)<<3)));
      const bf16x4 phi = *(const bf16x4*)(psrow + (((ct0^hi2)<<5) | (((g0+1)^lo2)<<3)));
      bf16x8 pf;
      pf[0]=plo[0]; pf[1]=plo[1]; pf[2]=plo[2]; pf[3]=plo[3];
      pf[4]=phi[0]; pf[5]=phi[1]; pf[6]=phi[2]; pf[7]=phi[3];
      const int c = ks*4 + quad;
      const int pp = (c & 8) | ((c & 7) ^ (l16 & 7));
#pragma unroll
      for (int t=0;t<5;t++){
        const bf16x8 vf = *(const bf16x8*)(Vs + (t*16+l16)*128 + pp*8);
        oacc[t] = __builtin_amdgcn_mfma_f32_16x16x32_bf16(pf, vf, oacc[t],0,0,0);
      }
    }
  }
  // denominator lives in oacc[4][r] at lanes l16==8 (dh==72 ones-row)
  float inv[4];
#pragma unroll
  for (int r=0;r<4;r++){
    const float lr = __shfl(oacc[4][r], quad*16 + 8, 64);
    inv[r] = 1.0f / lr;
  }
#pragma unroll
  for (int t=0;t<5;t++){
    const int dh = t*16+l16;
    if (dh < 72){
#pragma unroll
      for (int r=0;r<4;r++){
        const int q = wave*16 + quad*4 + r;
        const float v = oacc[t][r] * inv[r];
        outp[((size_t)bt*1024 + q0 + q)*1152 + hh*72 + dh] = __float2bfloat16(v);
      }
    }
  }
}

extern "C" void kernel_launch(void* const* d_in, const int* in_sizes, int n_in,
                              void* d_out, int out_size, void* d_ws, size_t ws_size,
                              hipStream_t stream)
{
  (void)in_sizes; (void)n_in; (void)out_size; (void)ws_size;
  const float* images = (const float*)d_in[0];
  const float* conv_w = (const float*)d_in[1];
  const float* conv_b = (const float*)d_in[2];
  const float* pos_emb= (const float*)d_in[3];
  const float* ln1_g  = (const float*)d_in[4];
  const float* ln1_b  = (const float*)d_in[5];
  const float* Wq     = (const float*)d_in[6];
  const float* bq     = (const float*)d_in[7];
  const float* Wk     = (const float*)d_in[8];
  const float* bk     = (const float*)d_in[9];
  const float* Wv     = (const float*)d_in[10];
  const float* bv     = (const float*)d_in[11];
  const float* Wo     = (const float*)d_in[12];
  const float* bo     = (const float*)d_in[13];
  const float* ln2_g  = (const float*)d_in[14];
  const float* ln2_b  = (const float*)d_in[15];
  const float* W1     = (const float*)d_in[16];
  const float* b1     = (const float*)d_in[17];
  const float* W2     = (const float*)d_in[18];
  const float* b2     = (const float*)d_in[19];
  const float* lnf_g  = (const float*)d_in[20];
  const float* lnf_b  = (const float*)d_in[21];

  char* p = (char*)d_ws;
  auto take = [&](size_t nbytes)->char*{ char* q = p; p += (nbytes + 255) & ~(size_t)255; return q; };
  float* xw   = (float*)take(4096ull*1152*4);
  bf16* hbuf  = (bf16*) take(4096ull*1152*2);
  bf16* h1    = (bf16*) take(4096ull*4352*2);
  bf16* qkvr  = h1;
  bf16* vbuf  = (bf16*) take(64ull*80*1024*2);
  bf16* imcol = vbuf;
  bf16* aout  = (bf16*) take(4096ull*1152*2);
  bf16* WqkvT = (bf16*) take(3456ull*1152*2);
  bf16* WoT   = (bf16*) take(1152ull*1152*2);
  bf16* W1T   = (bf16*) take(4352ull*1152*2);
  bf16* cwT   = W1T;
  bf16* W2T   = (bf16*) take(1152ull*4352*2);
  bf16* Ppart = (bf16*) take(4ull*4096*1152*2);  // bf16 split-K partials (max ks=4)
  float* bqkv = (float*)take(3456*4);
  float* b1p  = (float*)take(4352*4);
  float4* zbuf= (float4*)take(256);

  const float qscale = 1.4426950408889634f / sqrtf(72.0f);

  im2col_kernel<<<9728, 256, 0, stream>>>(images, imcol);
  transpose_cvt<<<dim3(36,19), 256, 0, stream>>>(conv_w, cwT, 588, 1152, 608, 1152);
  gemm_bf16<4><<<dim3(9,32,2), 256, 0, stream>>>(imcol, cwT, conv_b, Ppart, 1152, 608, 320, 0.f);

  for (int l=0;l<4;l++){
    transpose_cvt<<<dim3(36,36), 256, 0, stream>>>(Wq + (size_t)l*1152*1152, WqkvT,                1152,1152,1152,1152);
    transpose_cvt<<<dim3(36,36), 256, 0, stream>>>(Wk + (size_t)l*1152*1152, WqkvT + 1152ull*1152, 1152,1152,1152,1152);
    transpose_cvt<<<dim3(36,36), 256, 0, stream>>>(Wv + (size_t)l*1152*1152, WqkvT + 2304ull*1152, 1152,1152,1152,1152);
    transpose_cvt<<<dim3(36,36), 256, 0, stream>>>(Wo + (size_t)l*1152*1152, WoT, 1152,1152,1152,1152);
    transpose_cvt<<<dim3(136,36),256, 0, stream>>>(W1 + (size_t)l*1152*4304, W1T, 1152,4304,1152,4352);
    transpose_cvt<<<dim3(36,136),256, 0, stream>>>(W2 + (size_t)l*4304*1152, W2T, 4304,1152,4352,1152);
    pack_biases<<<17,256,0,stream>>>(bq,bk,bv,b1,l,bqkv,b1p,zbuf);

    if (l==0)
      ln_red<0,1><<<1024,256,0,stream>>>(pos_emb, 1023u, Ppart, 2, ln1_g, ln1_b, xw, hbuf);
    else
      ln_red<0,1><<<1024,256,0,stream>>>(xw, 4095u, Ppart, 4, ln1_g + l*1152, ln1_b + l*1152, xw, hbuf);

    gemm_bf16<3><<<dim3(27,32,1),256,0,stream>>>(hbuf, WqkvT, bqkv, qkvr, 3456, 1152, 1152, qscale);
    transpose_v<<<dim3(8,64),256,0,stream>>>(qkvr, vbuf);
    attn_kernel<<<dim3(16,64),256,0,stream>>>(qkvr, vbuf, zbuf, aout);
    gemm_bf16<4><<<dim3(9,32,3),256,0,stream>>>(aout, WoT, bo + l*1152, Ppart, 1152, 1152, 384, 0.f);
    ln_red<0,1><<<1024,256,0,stream>>>(xw, 4095u, Ppart, 3, ln2_g + l*1152, ln2_b + l*1152, xw, hbuf);

    gemm_bf16<1><<<dim3(34,32,1),256,0,stream>>>(hbuf, W1T, b1p, h1, 4352, 1152, 1152, 0.f);
    gemm_bf16<4><<<dim3(9,32,4),256,0,stream>>>(h1, W2T, b2 + l*1152, Ppart, 1152, 4352, 1088, 0.f);
  }
  ln_red<1,0><<<1024,256,0,stream>>>(xw, 4095u, Ppart, 4, lnf_g, lnf_b, nullptr, (float*)d_out);
}